// Round 5
// baseline (258.022 us; speedup 1.0000x reference)
//
#include <hip/hip_runtime.h>
#include <hip/hip_bf16.h>

#define N_NODES 50000
#define N_EDGES 800000
#define DIM 256      // input feature dim = K
#define QKDIM 256    // packed q|k per node (fp8: 256 B/row)
#define N_COPIES 8   // replicated diagA0 accumulators (atomic de-contention)
#define NB 391       // sort buckets: src >> 7 (128 nodes = 32 KB qk8 window)
#define NBLK 391     // sort pass blocks (2048 edges each)
#define EPB 2048     // edges per sort block
// pre = (0.5/H) * sum_A (q_s k_d + q_d k_s) = (full rotated 256-dot)/16

typedef __bf16 bfrag  __attribute__((ext_vector_type(8)));
typedef __bf16 bf4    __attribute__((ext_vector_type(4)));
typedef float  ffrag  __attribute__((ext_vector_type(4)));
typedef float  f2     __attribute__((ext_vector_type(2)));
typedef float  f4v    __attribute__((ext_vector_type(4)));

#define EP_PITCH 272   // epilogue LDS byte pitch (256+16)

// ---------------- prep: W' fp32->bf16 + zero accumulator region ----------------
__global__ __launch_bounds__(256) void prep_kernel(
    const float* __restrict__ Wq, const float* __restrict__ Wk,
    __bf16* __restrict__ Wb, float* __restrict__ out,
    float* __restrict__ priv, int flag)
{
    const int tid = blockIdx.x * 256 + threadIdx.x;
    const int i = tid * 4;
    if (i < 65536) {
        const float* s = (i < 32768) ? (Wq + i) : (Wk + (i - 32768));
        const float4 v = *(const float4*)s;
        bf4 o;
        o[0] = (__bf16)v.x; o[1] = (__bf16)v.y; o[2] = (__bf16)v.z; o[3] = (__bf16)v.w;
        *(bf4*)(Wb + i) = o;
    }
    if (flag) {
        if (tid < (N_COPIES * N_NODES) / 4)   // 100000 float4s
            ((float4*)priv)[tid] = make_float4(0.f, 0.f, 0.f, 0.f);
    } else {
        if (i + 4 <= N_NODES)
            *(float4*)(out + i) = make_float4(0.f, 0.f, 0.f, 0.f);
    }
}

// ---------------- counting sort by src bucket: 4 passes ----------------
// S1: per-block histogram -> histg[bucket][block]
__global__ __launch_bounds__(256) void sort_hist(
    const int* __restrict__ edge_index, int* __restrict__ histg)
{
    __shared__ int h[NB];
    const int tid = threadIdx.x;
    for (int b = tid; b < NB; b += 256) h[b] = 0;
    __syncthreads();
    const int base = blockIdx.x * EPB;
    #pragma unroll
    for (int i = 0; i < 8; ++i) {
        const int e = base + i * 256 + tid;
        if (e < N_EDGES) atomicAdd(&h[edge_index[e] >> 7], 1);
    }
    __syncthreads();
    for (int b = tid; b < NB; b += 256)
        histg[b * NBLK + blockIdx.x] = h[b];
}

// S2a: per-bucket exclusive scan over blocks (1 wave per bucket)
__global__ __launch_bounds__(64) void sort_scan_a(
    const int* __restrict__ histg, int* __restrict__ offs, int* __restrict__ total)
{
    const int b = blockIdx.x;
    const int l = threadIdx.x;
    int carry = 0;
    for (int c = 0; c < NBLK; c += 64) {
        const int idx = c + l;
        int v = (idx < NBLK) ? histg[b * NBLK + idx] : 0;
        int s = v;
        #pragma unroll
        for (int d = 1; d < 64; d <<= 1) {
            const int t = __shfl_up(s, d, 64);
            if (l >= d) s += t;
        }
        if (idx < NBLK) offs[b * NBLK + idx] = carry + s - v;   // exclusive
        carry += __shfl(s, 63, 64);
    }
    if (l == 0) total[b] = carry;
}

// S2b: exclusive scan of bucket totals -> basep (1 wave)
__global__ __launch_bounds__(64) void sort_scan_b(
    const int* __restrict__ total, int* __restrict__ basep)
{
    const int l = threadIdx.x;
    int carry = 0;
    for (int c = 0; c < NB; c += 64) {
        const int idx = c + l;
        int v = (idx < NB) ? total[idx] : 0;
        int s = v;
        #pragma unroll
        for (int d = 1; d < 64; d <<= 1) {
            const int t = __shfl_up(s, d, 64);
            if (l >= d) s += t;
        }
        if (idx < NB) basep[idx] = carry + s - v;
        carry += __shfl(s, 63, 64);
    }
}

// S3: scatter permuted records (src, dst, t0, t1) + original edge id
__global__ __launch_bounds__(256) void sort_scatter(
    const int* __restrict__ edge_index, const int* __restrict__ d0,
    const int* __restrict__ offs, const int* __restrict__ basep,
    int4* __restrict__ recA, int* __restrict__ recE)
{
    __shared__ int cur[NB];
    const int tid = threadIdx.x;
    for (int b = tid; b < NB; b += 256)
        cur[b] = basep[b] + offs[b * NBLK + blockIdx.x];
    __syncthreads();
    const int base = blockIdx.x * EPB;
    #pragma unroll
    for (int i = 0; i < 8; ++i) {
        const int e = base + i * 256 + tid;
        if (e < N_EDGES) {
            const int src = edge_index[e];
            const int dst = edge_index[N_EDGES + e];
            const int2 t01 = *(const int2*)(d0 + 2 * e);
            const int pos = atomicAdd(&cur[src >> 7], 1);
            recA[pos] = make_int4(src, dst, t01.x, t01.y);
            recE[pos] = e;
        }
    }
}

// ---------------- Projection via MFMA bf16 (unchanged) ----------------
__global__ __launch_bounds__(256) void proj_mfma(
    const float* __restrict__ x,
    const __bf16* __restrict__ Wb,
    const float* __restrict__ bq, const float* __restrict__ bk,
    unsigned char* __restrict__ qk8)
{
    __shared__ __bf16 As[64 * 256];   // 32 KB, fragment-order; reused by epilogue

    const int tid  = threadIdx.x;
    const int wv   = tid >> 6;
    const int lane = tid & 63;
    const int m    = lane & 15;
    const int q    = lane >> 4;
    const int mbase = blockIdx.x * 64;

    {
        const int srow = tid >> 2;
        const int c4   = tid & 3;
        int grow = mbase + srow;
        grow = grow < N_NODES ? grow : N_NODES - 1;
        const float* xp = x + (size_t)grow * DIM;
        const int mt_ = srow >> 4, m_ = srow & 15;
        #pragma unroll
        for (int i = 0; i < 16; ++i) {
            const int k = c4 * 4 + 16 * i;
            const f4v v = __builtin_nontemporal_load((const f4v*)(xp + k));
            bf4 o;
            o[0] = (__bf16)v[0]; o[1] = (__bf16)v[1];
            o[2] = (__bf16)v[2]; o[3] = (__bf16)v[3];
            const int seg = (k >> 5) * 4 + mt_;
            const int ln  = ((k >> 3) & 3) * 16 + m_;
            *(bf4*)(As + seg * 512 + ln * 8 + (k & 7)) = o;
        }
    }
    __syncthreads();

    ffrag acc[4][4] = {};

    #pragma unroll
    for (int h = 0; h < 2; ++h) {
        bfrag b[4][4];
        #pragma unroll
        for (int sp = 0; sp < 4; ++sp)
            #pragma unroll
            for (int nt = 0; nt < 4; ++nt) {
                const int col = wv * 64 + nt * 16 + m;
                b[sp][nt] = *(const bfrag*)(Wb + (size_t)col * DIM
                                            + 32 * (4 * h + sp) + 8 * q);
            }
        #pragma unroll
        for (int sp = 0; sp < 4; ++sp) {
            bfrag a[4];
            #pragma unroll
            for (int mt = 0; mt < 4; ++mt)
                a[mt] = *(const bfrag*)(As + ((4 * h + sp) * 4 + mt) * 512 + lane * 8);
            #pragma unroll
            for (int mt = 0; mt < 4; ++mt)
                #pragma unroll
                for (int nt = 0; nt < 4; ++nt)
                    acc[mt][nt] = __builtin_amdgcn_mfma_f32_16x16x32_bf16(
                                      a[mt], b[sp][nt], acc[mt][nt], 0, 0, 0);
        }
    }

    __syncthreads();
    unsigned char* ep = (unsigned char*)As;
    #pragma unroll
    for (int nt = 0; nt < 4; ++nt) {
        const int col  = wv * 64 + nt * 16 + m;
        const float bias = (col < 128) ? bq[col] : bk[col - 128];
        #pragma unroll
        for (int mt = 0; mt < 4; ++mt) {
            #pragma unroll
            for (int r = 0; r < 4; ++r) {
                const int rl = mt * 16 + q * 4 + r;
                const float v = acc[mt][nt][r] + bias;
                const int pk = __builtin_amdgcn_cvt_pk_fp8_f32(v, v, 0, false);
                ep[rl * EP_PITCH + col] = (unsigned char)(pk & 0xFF);
            }
        }
    }
    __syncthreads();
    {
        const int rl = tid >> 2;
        const int ch = tid & 3;
        const int grow = mbase + rl;
        if (grow < N_NODES) {
            const uint4* s4 = (const uint4*)(ep + rl * EP_PITCH + ch * 64);
            const uint4 t0 = s4[0], t1 = s4[1], t2 = s4[2], t3 = s4[3];
            uint4* g = (uint4*)(qk8 + (size_t)grow * QKDIM + ch * 64);
            g[0] = t0; g[1] = t1; g[2] = t2; g[3] = t3;
        }
    }
}

// ---------------- Edge scoring on SORTED records ----------------
// 4 lanes/edge, 16 edges/wave; src rows bucket-local (32 KB window -> L1/L2);
// XCD-bijective swizzle keeps each bucket's blocks on one XCD's L2.
__global__ __launch_bounds__(256) void edge_kernel_sorted(
    const unsigned char* __restrict__ qk8,
    const int4* __restrict__ recA, const int* __restrict__ recE,
    float* __restrict__ out, float* __restrict__ accum, int copymask)
{
    // bijective XCD swizzle (m204 form): phys blockIdx -> logical block lb
    const int nwg = gridDim.x;
    const int q8 = nwg >> 3, r8 = nwg & 7;
    const int xcd = blockIdx.x & 7, sub = blockIdx.x >> 3;
    const int lb = (xcd < r8 ? xcd * (q8 + 1) : r8 * (q8 + 1) + (xcd - r8) * q8) + sub;

    const int lane = threadIdx.x & 63;
    const int wave = lb * 4 + (threadIdx.x >> 6);
    const int g = lane >> 2;
    const int j = lane & 3;
    const int slot = wave * 16 + g;

    float* myacc = accum + (size_t)(blockIdx.x & copymask) * N_NODES;

    const int4 rec = recA[slot];           // 4 lanes share the address (L1 bcast)
    const int src = rec.x, dst = rec.y;

    const uint4* rs = (const uint4*)(qk8 + (size_t)src * QKDIM + 64 * j);
    const uint4* rd = (const uint4*)(qk8 + (size_t)dst * QKDIM + 64 * ((j + 2) & 3));

    uint4 a[4], b[4];
    #pragma unroll
    for (int i = 0; i < 4; ++i) { a[i] = rs[i]; b[i] = rd[i]; }

    f2 acc = {0.f, 0.f};
    #pragma unroll
    for (int i = 0; i < 4; ++i) {
        const unsigned int* ua = (const unsigned int*)&a[i];
        const unsigned int* ub = (const unsigned int*)&b[i];
        #pragma unroll
        for (int t = 0; t < 4; ++t) {
            const f2 x0 = __builtin_amdgcn_cvt_pk_f32_fp8(ua[t], false);
            const f2 y0 = __builtin_amdgcn_cvt_pk_f32_fp8(ub[t], false);
            const f2 x1 = __builtin_amdgcn_cvt_pk_f32_fp8(ua[t], true);
            const f2 y1 = __builtin_amdgcn_cvt_pk_f32_fp8(ub[t], true);
            acc += x0 * y0;
            acc += x1 * y1;
        }
    }
    float p = acc[0] + acc[1];
    p += __shfl_xor(p, 1, 64);
    p += __shfl_xor(p, 2, 64);

    if (j < 2) {
        const float val = __expf(p * 0.0625f);   // /16 = 0.5 * mean over 8 heads
        if (j == 0) out[N_NODES + recE[slot]] = val;   // diagA1 (un-permuted)
        atomicAdd(&myacc[j == 0 ? rec.z : rec.w], val);
    }
}

// ---------------- fallback: unsorted edge kernel (ws too small) ----------------
__global__ __launch_bounds__(256) void edge_kernel(
    const unsigned char* __restrict__ qk8,
    const int* __restrict__ edge_index, const int* __restrict__ d0,
    float* __restrict__ out, float* __restrict__ accum, int copymask)
{
    const int wave = (blockIdx.x * blockDim.x + threadIdx.x) >> 6;
    const int lane = threadIdx.x & 63;
    const int g = lane >> 2, j = lane & 3;
    const int e = wave * 16 + g;

    float* myacc = accum + (size_t)(blockIdx.x & copymask) * N_NODES;
    const int src = edge_index[e];
    const int dst = edge_index[N_EDGES + e];

    const uint4* rs = (const uint4*)(qk8 + (size_t)src * QKDIM + 64 * j);
    const uint4* rd = (const uint4*)(qk8 + (size_t)dst * QKDIM + 64 * ((j + 2) & 3));

    uint4 a[4], b[4];
    #pragma unroll
    for (int i = 0; i < 4; ++i) { a[i] = rs[i]; b[i] = rd[i]; }

    f2 acc = {0.f, 0.f};
    #pragma unroll
    for (int i = 0; i < 4; ++i) {
        const unsigned int* ua = (const unsigned int*)&a[i];
        const unsigned int* ub = (const unsigned int*)&b[i];
        #pragma unroll
        for (int t = 0; t < 4; ++t) {
            const f2 x0 = __builtin_amdgcn_cvt_pk_f32_fp8(ua[t], false);
            const f2 y0 = __builtin_amdgcn_cvt_pk_f32_fp8(ub[t], false);
            const f2 x1 = __builtin_amdgcn_cvt_pk_f32_fp8(ua[t], true);
            const f2 y1 = __builtin_amdgcn_cvt_pk_f32_fp8(ub[t], true);
            acc += x0 * y0;
            acc += x1 * y1;
        }
    }
    float p = acc[0] + acc[1];
    p += __shfl_xor(p, 1, 64);
    p += __shfl_xor(p, 2, 64);

    if (j < 2) {
        const float val = __expf(p * 0.0625f);
        const int target = d0[2 * e + j];
        if (j == 0) out[N_NODES + e] = val;
        atomicAdd(&myacc[target], val);
    }
}

// ---------------- reduce: out[n] = sum over copies of priv[c][n] ----------------
__global__ __launch_bounds__(256) void reduce_kernel(
    const float* __restrict__ priv, float* __restrict__ out)
{
    const int idx = (blockIdx.x * 256 + threadIdx.x) * 4;
    if (idx < N_NODES) {
        f4v s = __builtin_nontemporal_load((const f4v*)(priv + idx));
        #pragma unroll
        for (int c = 1; c < N_COPIES; ++c)
            s += __builtin_nontemporal_load((const f4v*)(priv + (size_t)c * N_NODES + idx));
        *(f4v*)(out + idx) = s;
    }
}

extern "C" void kernel_launch(void* const* d_in, const int* in_sizes, int n_in,
                              void* d_out, int out_size, void* d_ws, size_t ws_size,
                              hipStream_t stream) {
    const float* x  = (const float*)d_in[0];
    const float* Wq = (const float*)d_in[1];
    const float* bq = (const float*)d_in[2];
    const float* Wk = (const float*)d_in[3];
    const float* bk = (const float*)d_in[4];
    const int* edge_index = (const int*)d_in[5];
    const int* d0 = (const int*)d_in[6] + 2 * N_EDGES;  // row 1 of d0_index
    float* out = (float*)d_out;

    char* w = (char*)d_ws;
    unsigned char* qk8 = (unsigned char*)w;           w += (size_t)N_NODES * QKDIM;   // 12.8 MB
    __bf16* Wb = (__bf16*)w;                          w += 131072;
    float* priv = (float*)w;                          w += (size_t)N_COPIES * N_NODES * 4;
    int4* recA = (int4*)w;                            w += (size_t)N_EDGES * 16;      // 12.8 MB
    int* recE = (int*)w;                              w += (size_t)N_EDGES * 4;       // 3.2 MB
    int* histg = (int*)w;                             w += 611584;                    // NB*NBLK*4 padded
    int* offs = (int*)w;                              w += 611584;
    int* total = (int*)w;                             w += 1600;
    int* basep = (int*)w;                             w += 1600;

    const size_t need_sort = (size_t)(w - (char*)d_ws);
    const size_t need_priv = (size_t)N_NODES * QKDIM + 131072
                           + (size_t)N_COPIES * N_NODES * 4;
    const int use_sort = (ws_size >= need_sort) ? 1 : 0;
    const int use_priv = (ws_size >= need_priv) ? 1 : 0;
    float* accum = use_priv ? priv : out;
    const int copymask = use_priv ? (N_COPIES - 1) : 0;

    prep_kernel<<<391, 256, 0, stream>>>(Wq, Wk, Wb, out, priv, use_priv);
    proj_mfma<<<(N_NODES + 63) / 64, 256, 0, stream>>>(x, Wb, bq, bk, qk8);

    if (use_sort) {
        sort_hist<<<NBLK, 256, 0, stream>>>(edge_index, histg);
        sort_scan_a<<<NB, 64, 0, stream>>>(histg, offs, total);
        sort_scan_b<<<1, 64, 0, stream>>>(total, basep);
        sort_scatter<<<NBLK, 256, 0, stream>>>(edge_index, d0, offs, basep, recA, recE);
        edge_kernel_sorted<<<N_EDGES / 64, 256, 0, stream>>>(qk8, recA, recE, out,
                                                             accum, copymask);
    } else {
        edge_kernel<<<N_EDGES / 64, 256, 0, stream>>>(qk8, edge_index, d0, out,
                                                      accum, copymask);
    }
    if (use_priv)
        reduce_kernel<<<(N_NODES / 4 + 255) / 256, 256, 0, stream>>>(priv, out);
}

// Round 6
// 207.539 us; speedup vs baseline: 1.2432x; 1.2432x over previous
//
#include <hip/hip_runtime.h>
#include <hip/hip_bf16.h>

#define N_NODES 50000
#define N_EDGES 800000
#define DIM 256      // input feature dim = K
#define QKDIM 256    // packed q|k per node (fp8: 256 B/row)
#define NB_T  391    // target buckets: d0 >> 7 (128 nodes per bucket)
#define CAP   8192   // per-bucket record capacity (mean 4092, sigma ~64)
#define ITEMS (2 * N_EDGES)
#define IPB   4096   // items per prep_bin block (391 * 4096 >= 1.6M)
// pre = (0.5/H) * sum_A (q_s k_d + q_d k_s) = (full rotated 256-dot)/16

typedef __bf16 bfrag  __attribute__((ext_vector_type(8)));
typedef __bf16 bf4    __attribute__((ext_vector_type(4)));
typedef float  ffrag  __attribute__((ext_vector_type(4)));
typedef float  f2     __attribute__((ext_vector_type(2)));
typedef float  f4v    __attribute__((ext_vector_type(4)));

#define EP_PITCH 272   // epilogue LDS byte pitch (256+16)

// ---------------- prep_bin: W' fp32->bf16 + bin d0 items by target bucket ----
// Binning: per-block LDS hist -> one global chunk-reservation atomic per
// (block,bucket) (~150K atomics total) -> packed records (local<<20 | edge).
__global__ __launch_bounds__(256) void prep_bin(
    const float* __restrict__ Wq, const float* __restrict__ Wk,
    __bf16* __restrict__ Wb,
    const int* __restrict__ d0, unsigned int* __restrict__ rec,
    int* __restrict__ cur)
{
    __shared__ int lcnt[NB_T];
    __shared__ int lbase[NB_T];
    const int tid = threadIdx.x;
    const int gtid = blockIdx.x * 256 + tid;

    // ---- W convert (first 16384 gtids cover 65536 floats) ----
    const int i4 = gtid * 4;
    if (i4 < 65536) {
        const float* s = (i4 < 32768) ? (Wq + i4) : (Wk + (i4 - 32768));
        const float4 v = *(const float4*)s;
        bf4 o;
        o[0] = (__bf16)v.x; o[1] = (__bf16)v.y; o[2] = (__bf16)v.z; o[3] = (__bf16)v.w;
        *(bf4*)(Wb + i4) = o;
    }

    // ---- pass 1: count this block's items per bucket ----
    for (int b = tid; b < NB_T; b += 256) lcnt[b] = 0;
    __syncthreads();
    const int base = blockIdx.x * IPB;
    int tg[16];
    #pragma unroll
    for (int r = 0; r < 16; ++r) {
        const int i = base + r * 256 + tid;
        tg[r] = (i < ITEMS) ? d0[i] : -1;
        if (tg[r] >= 0) atomicAdd(&lcnt[tg[r] >> 7], 1);
    }
    __syncthreads();

    // ---- reserve contiguous chunks in each bucket ----
    for (int b = tid; b < NB_T; b += 256) {
        const int c = lcnt[b];
        lbase[b] = c ? atomicAdd(&cur[b], c) : 0;
    }
    __syncthreads();
    for (int b = tid; b < NB_T; b += 256) lcnt[b] = 0;   // reuse as offset
    __syncthreads();

    // ---- pass 2: write packed records ----
    #pragma unroll
    for (int r = 0; r < 16; ++r) {
        if (tg[r] >= 0) {
            const int i = base + r * 256 + tid;
            const int b = tg[r] >> 7;
            const int off = atomicAdd(&lcnt[b], 1);
            rec[(size_t)b * CAP + lbase[b] + off] =
                ((unsigned int)(tg[r] & 127) << 20) | (unsigned int)(i >> 1);
        }
    }
}

// ---------------- Projection via MFMA bf16 (unchanged, known-good) ----------
__global__ __launch_bounds__(256) void proj_mfma(
    const float* __restrict__ x,
    const __bf16* __restrict__ Wb,
    const float* __restrict__ bq, const float* __restrict__ bk,
    unsigned char* __restrict__ qk8)
{
    __shared__ __bf16 As[64 * 256];   // 32 KB, fragment-order; reused by epilogue

    const int tid  = threadIdx.x;
    const int wv   = tid >> 6;
    const int lane = tid & 63;
    const int m    = lane & 15;
    const int q    = lane >> 4;
    const int mbase = blockIdx.x * 64;

    {
        const int srow = tid >> 2;
        const int c4   = tid & 3;
        int grow = mbase + srow;
        grow = grow < N_NODES ? grow : N_NODES - 1;
        const float* xp = x + (size_t)grow * DIM;
        const int mt_ = srow >> 4, m_ = srow & 15;
        #pragma unroll
        for (int i = 0; i < 16; ++i) {
            const int k = c4 * 4 + 16 * i;
            const f4v v = __builtin_nontemporal_load((const f4v*)(xp + k));
            bf4 o;
            o[0] = (__bf16)v[0]; o[1] = (__bf16)v[1];
            o[2] = (__bf16)v[2]; o[3] = (__bf16)v[3];
            const int seg = (k >> 5) * 4 + mt_;
            const int ln  = ((k >> 3) & 3) * 16 + m_;
            *(bf4*)(As + seg * 512 + ln * 8 + (k & 7)) = o;
        }
    }
    __syncthreads();

    ffrag acc[4][4] = {};

    #pragma unroll
    for (int h = 0; h < 2; ++h) {
        bfrag b[4][4];
        #pragma unroll
        for (int sp = 0; sp < 4; ++sp)
            #pragma unroll
            for (int nt = 0; nt < 4; ++nt) {
                const int col = wv * 64 + nt * 16 + m;
                b[sp][nt] = *(const bfrag*)(Wb + (size_t)col * DIM
                                            + 32 * (4 * h + sp) + 8 * q);
            }
        #pragma unroll
        for (int sp = 0; sp < 4; ++sp) {
            bfrag a[4];
            #pragma unroll
            for (int mt = 0; mt < 4; ++mt)
                a[mt] = *(const bfrag*)(As + ((4 * h + sp) * 4 + mt) * 512 + lane * 8);
            #pragma unroll
            for (int mt = 0; mt < 4; ++mt)
                #pragma unroll
                for (int nt = 0; nt < 4; ++nt)
                    acc[mt][nt] = __builtin_amdgcn_mfma_f32_16x16x32_bf16(
                                      a[mt], b[sp][nt], acc[mt][nt], 0, 0, 0);
        }
    }

    __syncthreads();
    unsigned char* ep = (unsigned char*)As;
    #pragma unroll
    for (int nt = 0; nt < 4; ++nt) {
        const int col  = wv * 64 + nt * 16 + m;
        const float bias = (col < 128) ? bq[col] : bk[col - 128];
        #pragma unroll
        for (int mt = 0; mt < 4; ++mt) {
            #pragma unroll
            for (int r = 0; r < 4; ++r) {
                const int rl = mt * 16 + q * 4 + r;
                const float v = acc[mt][nt][r] + bias;
                const int pk = __builtin_amdgcn_cvt_pk_fp8_f32(v, v, 0, false);
                ep[rl * EP_PITCH + col] = (unsigned char)(pk & 0xFF);
            }
        }
    }
    __syncthreads();
    {
        const int rl = tid >> 2;
        const int ch = tid & 3;
        const int grow = mbase + rl;
        if (grow < N_NODES) {
            const uint4* s4 = (const uint4*)(ep + rl * EP_PITCH + ch * 64);
            const uint4 t0 = s4[0], t1 = s4[1], t2 = s4[2], t3 = s4[3];
            uint4* g = (uint4*)(qk8 + (size_t)grow * QKDIM + ch * 64);
            g[0] = t0; g[1] = t1; g[2] = t2; g[3] = t3;
        }
    }
}

// ---------------- Edge scoring: gather + dot + exp, NO atomics --------------
// 4 lanes per edge, 16 edges per wave. Lane j covers src bytes [64j, +64);
// dst bytes 64*((j+2)&3) (the (t+128)&255 q|k rotation).  [R4 known-good]
__global__ __launch_bounds__(256) void edge_compute(
    const unsigned char* __restrict__ qk8,
    const int* __restrict__ edge_index,   // [2][E]
    float* __restrict__ out)              // writes diagA1 = out[N..N+E)
{
    const int wave = (blockIdx.x * blockDim.x + threadIdx.x) >> 6;
    const int lane = threadIdx.x & 63;
    const int g = lane >> 2;              // edge within wave (0..15)
    const int j = lane & 3;               // lane within edge
    const int e = wave * 16 + g;          // 800000 = 50000*16, no tail

    const int src = __builtin_nontemporal_load(edge_index + e);
    const int dst = __builtin_nontemporal_load(edge_index + N_EDGES + e);

    const uint4* rs = (const uint4*)(qk8 + (size_t)src * QKDIM + 64 * j);
    const uint4* rd = (const uint4*)(qk8 + (size_t)dst * QKDIM + 64 * ((j + 2) & 3));

    uint4 a[4], b[4];
    #pragma unroll
    for (int i = 0; i < 4; ++i) { a[i] = rs[i]; b[i] = rd[i]; }

    f2 acc = {0.f, 0.f};
    #pragma unroll
    for (int i = 0; i < 4; ++i) {
        const unsigned int* ua = (const unsigned int*)&a[i];
        const unsigned int* ub = (const unsigned int*)&b[i];
        #pragma unroll
        for (int t = 0; t < 4; ++t) {
            const f2 x0 = __builtin_amdgcn_cvt_pk_f32_fp8(ua[t], false);
            const f2 y0 = __builtin_amdgcn_cvt_pk_f32_fp8(ub[t], false);
            const f2 x1 = __builtin_amdgcn_cvt_pk_f32_fp8(ua[t], true);
            const f2 y1 = __builtin_amdgcn_cvt_pk_f32_fp8(ub[t], true);
            acc += x0 * y0;
            acc += x1 * y1;
        }
    }
    float p = acc[0] + acc[1];

    p += __shfl_xor(p, 1, 64);
    p += __shfl_xor(p, 2, 64);

    if (j == 0)
        out[N_NODES + e] = __expf(p * 0.0625f);   // /16 = 0.5 * mean over 8 heads
}

// ---------------- phase_scatter: per-bucket LDS aggregation -> plain stores -
// Block b owns nodes [128b, 128b+128): reads its bucket's records, gathers
// val[e] from diagA1 (L2-resident), LDS-atomicAdd, then unique-writer stores.
// Zero global atomics; out[0..N) needs no pre-zeroing.
__global__ __launch_bounds__(1024) void phase_scatter(
    const unsigned int* __restrict__ rec, const int* __restrict__ cur,
    float* __restrict__ out)
{
    __shared__ float acc[128];
    const int b = blockIdx.x;
    const int tid = threadIdx.x;
    if (tid < 128) acc[tid] = 0.f;
    __syncthreads();

    const int cnt = cur[b];
    const unsigned int* rb = rec + (size_t)b * CAP;
    for (int i = tid; i < cnt; i += 1024) {
        const unsigned int r = rb[i];
        const float v = out[N_NODES + (r & 0xFFFFF)];
        atomicAdd(&acc[r >> 20], v);
    }
    __syncthreads();

    if (tid < 128) {
        const int n = b * 128 + tid;
        if (n < N_NODES) out[n] = acc[tid];
    }
}

extern "C" void kernel_launch(void* const* d_in, const int* in_sizes, int n_in,
                              void* d_out, int out_size, void* d_ws, size_t ws_size,
                              hipStream_t stream) {
    const float* x  = (const float*)d_in[0];
    const float* Wq = (const float*)d_in[1];
    const float* bq = (const float*)d_in[2];
    const float* Wk = (const float*)d_in[3];
    const float* bk = (const float*)d_in[4];
    const int* edge_index = (const int*)d_in[5];
    const int* d0 = (const int*)d_in[6] + 2 * N_EDGES;  // row 1 of d0_index
    float* out = (float*)d_out;

    char* w = (char*)d_ws;
    unsigned char* qk8 = (unsigned char*)w;  w += (size_t)N_NODES * QKDIM;  // 12.8 MB
    __bf16* Wb = (__bf16*)w;                 w += 131072;                   // 128 KB
    unsigned int* rec = (unsigned int*)w;    w += (size_t)NB_T * CAP * 4;   // 12.8 MB
    int* cur = (int*)w;                      w += 2048;

    hipMemsetAsync(cur, 0, NB_T * sizeof(int), stream);
    prep_bin<<<NB_T, 256, 0, stream>>>(Wq, Wk, Wb, d0, rec, cur);
    proj_mfma<<<(N_NODES + 63) / 64, 256, 0, stream>>>(x, Wb, bq, bk, qk8);
    edge_compute<<<N_EDGES / 64, 256, 0, stream>>>(qk8, edge_index, out);
    phase_scatter<<<NB_T, 1024, 0, stream>>>(rec, cur, out);
}